// Round 1
// baseline (298.870 us; speedup 1.0000x reference)
//
#include <hip/hip_runtime.h>
#include <math.h>

// Problem constants
#define NT 16    // tasks
#define NR 25    // rows (shot*way) per task
#define DZ 512   // d
#define D2Z 1024 // 2d
#define NC 64    // concepts

// Workspace layout (floats):
//  Dm      [16][25][25]        off 0          size 10000
//  cntPart [16][5]             off 10000      size 80
//  A       [16][3][25][1024]   off 10080      size 1228800
//  Gpart   [16][5][1024]       off 1238880    size 81920
//  pooled  [16][512]           off 1320800    size 8192
//  u       [16][1024]          off 1328992    size 16384
//  o       [16][512]           off 1345376    size 8192
// total 1353568 floats = 5.42 MB

// ---------------------------------------------------------------------------
// K1: normalized pairwise L2 distance rows. One block (64 threads = 1 wave)
// per (task k, anchor row a). D[k][a][j] = || xn_a - xn_j ||_2 with
// xn = x / ||x||, computed exactly as reference: sq_i + sq_j - 2*dot.
// ---------------------------------------------------------------------------
__global__ __launch_bounds__(64) void k_dist(const float* __restrict__ x,
                                             float* __restrict__ Dm)
{
    int k = blockIdx.x, a = blockIdx.y;
    int lane = threadIdx.x;
    const float* xk = x + (size_t)k * NR * DZ;

    const float4* xap = (const float4*)(xk + a * DZ);
    float4 a0 = xap[lane];
    float4 a1 = xap[lane + 64];

    float sa = a0.x*a0.x + a0.y*a0.y + a0.z*a0.z + a0.w*a0.w
             + a1.x*a1.x + a1.y*a1.y + a1.z*a1.z + a1.w*a1.w;
    #pragma unroll
    for (int off = 32; off; off >>= 1) sa += __shfl_xor(sa, off);
    float inva = 1.0f / sqrtf(sa);
    a0.x *= inva; a0.y *= inva; a0.z *= inva; a0.w *= inva;
    a1.x *= inva; a1.y *= inva; a1.z *= inva; a1.w *= inva;
    float sqa = a0.x*a0.x + a0.y*a0.y + a0.z*a0.z + a0.w*a0.w
              + a1.x*a1.x + a1.y*a1.y + a1.z*a1.z + a1.w*a1.w;
    #pragma unroll
    for (int off = 32; off; off >>= 1) sqa += __shfl_xor(sqa, off);

    for (int j = 0; j < NR; j++) {
        const float4* xjp = (const float4*)(xk + j * DZ);
        float4 j0 = xjp[lane];
        float4 j1 = xjp[lane + 64];
        float sj = j0.x*j0.x + j0.y*j0.y + j0.z*j0.z + j0.w*j0.w
                 + j1.x*j1.x + j1.y*j1.y + j1.z*j1.z + j1.w*j1.w;
        #pragma unroll
        for (int off = 32; off; off >>= 1) sj += __shfl_xor(sj, off);
        float invj = 1.0f / sqrtf(sj);
        j0.x *= invj; j0.y *= invj; j0.z *= invj; j0.w *= invj;
        j1.x *= invj; j1.y *= invj; j1.z *= invj; j1.w *= invj;

        float sqj = j0.x*j0.x + j0.y*j0.y + j0.z*j0.z + j0.w*j0.w
                  + j1.x*j1.x + j1.y*j1.y + j1.z*j1.z + j1.w*j1.w;
        float dij = a0.x*j0.x + a0.y*j0.y + a0.z*j0.z + a0.w*j0.w
                  + a1.x*j1.x + a1.y*j1.y + a1.z*j1.z + a1.w*j1.w;
        #pragma unroll
        for (int off = 32; off; off >>= 1) {
            sqj += __shfl_xor(sqj, off);
            dij += __shfl_xor(dij, off);
        }
        float d2 = sqa + sqj - 2.0f * dij;
        float d  = sqrtf(fmaxf(d2, 0.0f));
        if (lane == 0) Dm[((size_t)k * NR + a) * NR + j] = d;
    }
}

// ---------------------------------------------------------------------------
// K2: A[k][c][i][j] = sum_r x[k][i][r] * W1[c*512 + r][j]  (no bias)
// grid (12 col-tiles of 256, 2 row-groups of 13 (row 12 duplicated), 16 tasks)
// x reads are block-uniform -> scalar loads; W1 reads coalesced.
// ---------------------------------------------------------------------------
__global__ __launch_bounds__(256) void k_gemm1(const float* __restrict__ x,
                                               const float* __restrict__ W1,
                                               float* __restrict__ A)
{
    int ct = blockIdx.x;   // 0..11
    int ig = blockIdx.y;   // 0..1
    int k  = blockIdx.z;   // 0..15
    int tid = threadIdx.x;
    int jg = ct * 256 + tid;        // 0..3071
    int c  = jg >> 10;              // 0..2
    int j  = jg & 1023;
    int i0 = ig * 12;               // rows i0..i0+12 (row 12 written twice, same bits)

    const float* xp = x + ((size_t)k * NR + i0) * DZ;
    const float* wp = W1 + (size_t)c * DZ * D2Z + j;

    float acc[13];
    #pragma unroll
    for (int u = 0; u < 13; u++) acc[u] = 0.0f;

    #pragma unroll 4
    for (int r = 0; r < DZ; r++) {
        float w = wp[(size_t)r * D2Z];
        #pragma unroll
        for (int u = 0; u < 13; u++)
            acc[u] = fmaf(xp[u * DZ + r], w, acc[u]);
    }

    float* Ab = A + (((size_t)k * 3 + c) * NR + i0) * D2Z + j;
    #pragma unroll
    for (int u = 0; u < 13; u++) Ab[(size_t)u * D2Z] = acc[u];
}

// ---------------------------------------------------------------------------
// K3: masked relu-accumulate over all triplets.
// G[k][j] = sum_{a,p,n} mask(k,a,p,n) * relu(A1[a][j]+A2[p][j]+A3[n][j]+b1[j])
// grid (4 j-tiles, 5 anchor-groups, 16 tasks). Mask computed on the fly from
// Dm (wave-uniform scalar loads). Also emits cnt (mask count) partials.
// ---------------------------------------------------------------------------
__global__ __launch_bounds__(256) void k_accum(const float* __restrict__ A,
                                               const float* __restrict__ Dm,
                                               const float* __restrict__ b1,
                                               float* __restrict__ Gpart,
                                               float* __restrict__ cntPart)
{
    int jt = blockIdx.x;   // 0..3
    int ag = blockIdx.y;   // 0..4
    int k  = blockIdx.z;   // 0..15
    int tid = threadIdx.x;
    int j = jt * 256 + tid;

    const float* Ab = A + (size_t)k * 75 * D2Z + j;
    float a2v[25], a3v[25];
    #pragma unroll
    for (int i = 0; i < 25; i++) a2v[i] = Ab[(size_t)(25 + i) * D2Z];
    #pragma unroll
    for (int i = 0; i < 25; i++) a3v[i] = Ab[(size_t)(50 + i) * D2Z];
    float b1v = b1[j];

    const float* Dk = Dm + (size_t)k * 625;
    float acc = 0.0f, cnt = 0.0f;

    for (int q = 0; q < 5; q++) {            // anchor a = ag*5+q, label q
        int a = ag * 5 + q;
        float a1 = Ab[(size_t)a * D2Z];
        #pragma unroll
        for (int m = 0; m < 5; m++) {        // positive p = q+5m, skip p==a (m==ag)
            int p = q + 5 * m;
            float dap = Dk[a * 25 + p];
            float s = a1 + a2v[p] + b1v;
            bool mval = (m != ag);
            #pragma unroll
            for (int n = 0; n < 25; n++) {   // negative: label(n) != q
                float dan = Dk[a * 25 + n];
                float tm = dan - dap;
                bool sel = mval && ((n % 5) != q) && (tm > 0.0f) && (tm <= 0.8f);
                float pre = fmaxf(s + a3v[n], 0.0f);
                float msk = sel ? 1.0f : 0.0f;
                acc = fmaf(msk, pre, acc);
                cnt += msk;
            }
        }
    }

    Gpart[((size_t)k * 5 + ag) * D2Z + j] = acc;
    if (jt == 0 && tid == 0) cntPart[k * 5 + ag] = cnt;
}

// ---------------------------------------------------------------------------
// K4a: pooled[k][s] = sum_j G[k][j]*W2[j][s] + cnt[k]*b2[s]
// Weight-stationary: grid 8 blocks x 1024 threads; all 16 tasks' G in LDS.
// ---------------------------------------------------------------------------
__global__ __launch_bounds__(1024) void k_pooled(const float* __restrict__ Gpart,
                                                 const float* __restrict__ cntPart,
                                                 const float* __restrict__ W2,
                                                 const float* __restrict__ b2,
                                                 float* __restrict__ pooled)
{
    __shared__ float G[NT * D2Z];  // 64 KB
    int tid = threadIdx.x;
    for (int idx = tid; idx < NT * D2Z; idx += 1024) {
        int kk = idx >> 10, j = idx & 1023;
        float s = 0.0f;
        #pragma unroll
        for (int ag = 0; ag < 5; ag++)
            s += Gpart[((size_t)kk * 5 + ag) * D2Z + j];
        G[idx] = s;
    }
    __syncthreads();

    int c  = tid & 63;
    int kk = tid >> 6;                 // wave-uniform
    int col = blockIdx.x * 64 + c;     // 0..511
    float cnt = 0.0f;
    #pragma unroll
    for (int ag = 0; ag < 5; ag++) cnt += cntPart[kk * 5 + ag];

    float acc = cnt * b2[col];
    for (int jj = 0; jj < D2Z; jj++)
        acc = fmaf(G[kk * D2Z + jj], W2[(size_t)jj * DZ + col], acc);
    pooled[kk * DZ + col] = acc;
}

// ---------------------------------------------------------------------------
// K4b: u[k][t] = relu(sum_s pooled[k][s]*W3[s][t] + b3[t]); grid 16 x 1024
// ---------------------------------------------------------------------------
__global__ __launch_bounds__(1024) void k_u(const float* __restrict__ pooled,
                                            const float* __restrict__ W3,
                                            const float* __restrict__ b3,
                                            float* __restrict__ u)
{
    __shared__ float P[NT * DZ];  // 32 KB
    int tid = threadIdx.x;
    for (int idx = tid; idx < NT * DZ; idx += 1024) P[idx] = pooled[idx];
    __syncthreads();

    int c  = tid & 63;
    int kk = tid >> 6;
    int col = blockIdx.x * 64 + c;     // 0..1023
    float acc = b3[col];
    for (int s = 0; s < DZ; s++)
        acc = fmaf(P[kk * DZ + s], W3[(size_t)s * D2Z + col], acc);
    u[kk * D2Z + col] = fmaxf(acc, 0.0f);
}

// ---------------------------------------------------------------------------
// K4c: o[k][s] = sum_t u[k][t]*W4[t][s] + b4[s]; grid 8 x 1024
// ---------------------------------------------------------------------------
__global__ __launch_bounds__(1024) void k_o(const float* __restrict__ u,
                                            const float* __restrict__ W4,
                                            const float* __restrict__ b4,
                                            float* __restrict__ o)
{
    __shared__ float U[NT * D2Z];  // 64 KB
    int tid = threadIdx.x;
    for (int idx = tid; idx < NT * D2Z; idx += 1024) U[idx] = u[idx];
    __syncthreads();

    int c  = tid & 63;
    int kk = tid >> 6;
    int col = blockIdx.x * 64 + c;     // 0..511
    float acc = b4[col];
    for (int jj = 0; jj < D2Z; jj++)
        acc = fmaf(U[kk * D2Z + jj], W4[(size_t)jj * DZ + col], acc);
    o[kk * DZ + col] = acc;
}

// ---------------------------------------------------------------------------
// K4d: score = o @ Wc + bc, softmax over 64 concepts. One block per task.
// ---------------------------------------------------------------------------
__global__ __launch_bounds__(256) void k_score(const float* __restrict__ o,
                                               const float* __restrict__ Wc,
                                               const float* __restrict__ bc,
                                               float* __restrict__ out)
{
    int k = blockIdx.x, tid = threadIdx.x;
    __shared__ float O[DZ];
    __shared__ float red[256];
    O[tid]       = o[(size_t)k * DZ + tid];
    O[256 + tid] = o[(size_t)k * DZ + 256 + tid];
    __syncthreads();

    int oc = tid & 63, chunk = tid >> 6;  // 4 chunks of 128
    float acc = 0.0f;
    for (int r = 0; r < 128; r++) {
        int rr = chunk * 128 + r;
        acc = fmaf(O[rr], Wc[(size_t)rr * NC + oc], acc);
    }
    red[tid] = acc;
    __syncthreads();

    if (tid < 64) {
        float sc = bc[tid] + red[tid] + red[64 + tid] + red[128 + tid] + red[192 + tid];
        float m = sc;
        #pragma unroll
        for (int off = 32; off; off >>= 1) m = fmaxf(m, __shfl_xor(m, off));
        float e = expf(sc - m);
        float ss = e;
        #pragma unroll
        for (int off = 32; off; off >>= 1) ss += __shfl_xor(ss, off);
        out[k * NC + tid] = e / ss;
    }
}

extern "C" void kernel_launch(void* const* d_in, const int* in_sizes, int n_in,
                              void* d_out, int out_size, void* d_ws, size_t ws_size,
                              hipStream_t stream)
{
    const float* x  = (const float*)d_in[0];
    const float* W1 = (const float*)d_in[1];
    const float* b1 = (const float*)d_in[2];
    const float* W2 = (const float*)d_in[3];
    const float* b2 = (const float*)d_in[4];
    const float* W3 = (const float*)d_in[5];
    const float* b3 = (const float*)d_in[6];
    const float* W4 = (const float*)d_in[7];
    const float* b4 = (const float*)d_in[8];
    const float* Wc = (const float*)d_in[9];
    const float* bc = (const float*)d_in[10];
    float* out = (float*)d_out;

    float* ws      = (float*)d_ws;
    float* Dm      = ws;                      // 10000
    float* cntPart = ws + 10000;              // 80
    float* A       = ws + 10080;              // 1228800
    float* Gpart   = A + 1228800;             // 81920
    float* pooled  = Gpart + 81920;           // 8192
    float* uu      = pooled + 8192;           // 16384
    float* oo      = uu + 16384;              // 8192

    k_dist  <<<dim3(NT, NR), 64,  0, stream>>>(x, Dm);
    k_gemm1 <<<dim3(12, 2, NT), 256, 0, stream>>>(x, W1, A);
    k_accum <<<dim3(4, 5, NT), 256, 0, stream>>>(A, Dm, b1, Gpart, cntPart);
    k_pooled<<<8,  1024, 0, stream>>>(Gpart, cntPart, W2, b2, pooled);
    k_u     <<<16, 1024, 0, stream>>>(pooled, W3, b3, uu);
    k_o     <<<8,  1024, 0, stream>>>(uu, W4, b4, oo);
    k_score <<<NT, 256, 0, stream>>>(oo, Wc, bc, out);
}

// Round 2
// 257.771 us; speedup vs baseline: 1.1594x; 1.1594x over previous
//
#include <hip/hip_runtime.h>
#include <math.h>

#define NT 16
#define NR 25
#define DZ 512
#define D2Z 1024
#define NC 64

// Workspace layout (floats):
//  Dm     [16][25][25]       off 0        size 10000
//  cnt    [16]               off 10000    size 16
//  G      [16][1024]         off 10016    size 16384   (zeroed each call)
//  A      [16][3][25][1024]  off 26400    size 1228800
//  pooled [16][512]          off 1255200  size 8192
//  u      [16][1024]         off 1263392  size 16384
//  o      [16][512]          off 1279776  size 8192

// ---------------------------------------------------------------------------
// K1: normalized pairwise distances. Block (k,a), 4 waves; wave w handles
// j = w, w+4, ... Same per-j arithmetic as the verified R1 kernel.
// ---------------------------------------------------------------------------
__global__ __launch_bounds__(256) void k_dist(const float* __restrict__ x,
                                              float* __restrict__ Dm)
{
    int k = blockIdx.x, a = blockIdx.y;
    int lane = threadIdx.x & 63;
    int w    = threadIdx.x >> 6;
    const float* xk = x + (size_t)k * NR * DZ;

    const float4* xap = (const float4*)(xk + a * DZ);
    float4 a0 = xap[lane];
    float4 a1 = xap[lane + 64];

    float sa = a0.x*a0.x + a0.y*a0.y + a0.z*a0.z + a0.w*a0.w
             + a1.x*a1.x + a1.y*a1.y + a1.z*a1.z + a1.w*a1.w;
    #pragma unroll
    for (int off = 32; off; off >>= 1) sa += __shfl_xor(sa, off);
    float inva = 1.0f / sqrtf(sa);
    a0.x *= inva; a0.y *= inva; a0.z *= inva; a0.w *= inva;
    a1.x *= inva; a1.y *= inva; a1.z *= inva; a1.w *= inva;
    float sqa = a0.x*a0.x + a0.y*a0.y + a0.z*a0.z + a0.w*a0.w
              + a1.x*a1.x + a1.y*a1.y + a1.z*a1.z + a1.w*a1.w;
    #pragma unroll
    for (int off = 32; off; off >>= 1) sqa += __shfl_xor(sqa, off);

    for (int j = w; j < NR; j += 4) {
        const float4* xjp = (const float4*)(xk + j * DZ);
        float4 j0 = xjp[lane];
        float4 j1 = xjp[lane + 64];
        float sj = j0.x*j0.x + j0.y*j0.y + j0.z*j0.z + j0.w*j0.w
                 + j1.x*j1.x + j1.y*j1.y + j1.z*j1.z + j1.w*j1.w;
        #pragma unroll
        for (int off = 32; off; off >>= 1) sj += __shfl_xor(sj, off);
        float invj = 1.0f / sqrtf(sj);
        j0.x *= invj; j0.y *= invj; j0.z *= invj; j0.w *= invj;
        j1.x *= invj; j1.y *= invj; j1.z *= invj; j1.w *= invj;

        float sqj = j0.x*j0.x + j0.y*j0.y + j0.z*j0.z + j0.w*j0.w
                  + j1.x*j1.x + j1.y*j1.y + j1.z*j1.z + j1.w*j1.w;
        float dij = a0.x*j0.x + a0.y*j0.y + a0.z*j0.z + a0.w*j0.w
                  + a1.x*j1.x + a1.y*j1.y + a1.z*j1.z + a1.w*j1.w;
        #pragma unroll
        for (int off = 32; off; off >>= 1) {
            sqj += __shfl_xor(sqj, off);
            dij += __shfl_xor(dij, off);
        }
        float d2 = sqa + sqj - 2.0f * dij;
        float d  = sqrtf(fmaxf(d2, 0.0f));
        if (lane == 0) Dm[((size_t)k * NR + a) * NR + j] = d;
    }
}

// ---------------------------------------------------------------------------
// K2: A[k][c][i][j] = sum_r x[k][i][r] * W1[c*512+r][j]
// Grid (48 coltiles of 64, 2 rowgroups of 13, 8 taskpairs). 256 thr =
// 64 cols x 4 K-chunks of 128. 26 accumulators/thread (13 rows x 2 tasks),
// LDS split-K reduce. x reads are wave-uniform (scalar path), W1 coalesced.
// ---------------------------------------------------------------------------
__global__ __launch_bounds__(256) void k_gemm1(const float* __restrict__ x,
                                               const float* __restrict__ W1,
                                               float* __restrict__ A)
{
    int ct = blockIdx.x;          // 0..47
    int ig = blockIdx.y;          // 0..1
    int tp = blockIdx.z;          // 0..7
    int tid  = threadIdx.x;
    int lane = tid & 63;
    int kc   = tid >> 6;          // K-chunk 0..3
    int jg   = ct * 64 + lane;    // 0..3071 (c uniform per wave)
    int c    = jg >> 10;
    int j    = jg & 1023;
    int i0   = ig * 12;           // rows i0..i0+12 (row 12 written twice, same value)
    int k0   = tp * 2;

    const float* xp = x + ((size_t)k0 * NR + i0) * DZ;
    const float* wp = W1 + (size_t)c * DZ * D2Z + j;

    float acc[26];
    #pragma unroll
    for (int u = 0; u < 26; u++) acc[u] = 0.0f;

    int r0 = kc * 128;
    #pragma unroll 4
    for (int r = r0; r < r0 + 128; r++) {
        float w = wp[(size_t)r * D2Z];
        #pragma unroll
        for (int u = 0; u < 13; u++)
            acc[u] = fmaf(xp[u * DZ + r], w, acc[u]);
        #pragma unroll
        for (int u = 0; u < 13; u++)
            acc[13 + u] = fmaf(xp[NR * DZ + u * DZ + r], w, acc[13 + u]);
    }

    __shared__ float red[4][26][64];
    #pragma unroll
    for (int u = 0; u < 26; u++) red[kc][u][lane] = acc[u];
    __syncthreads();

    for (int idx = tid; idx < 26 * 64; idx += 256) {
        int u  = idx >> 6;
        int ln = idx & 63;
        float s = red[0][u][ln] + red[1][u][ln] + red[2][u][ln] + red[3][u][ln];
        int kk = k0 + (u >= 13 ? 1 : 0);
        int i  = i0 + (u >= 13 ? u - 13 : u);
        int jg2 = ct * 64 + ln;
        int c2  = jg2 >> 10;
        int j2  = jg2 & 1023;
        A[(((size_t)kk * 3 + c2) * NR + i) * D2Z + j2] = s;
    }
}

// ---------------------------------------------------------------------------
// K3: masked relu-accumulate, one anchor per block-row.
// Grid (4 jtiles, 25 anchors, 16 tasks). atomicAdd into zeroed G / cnt.
// ---------------------------------------------------------------------------
__global__ __launch_bounds__(256) void k_accum(const float* __restrict__ A,
                                               const float* __restrict__ Dm,
                                               const float* __restrict__ b1,
                                               float* __restrict__ G,
                                               float* __restrict__ cnt)
{
    int jt = blockIdx.x;   // 0..3
    int a  = blockIdx.y;   // 0..24
    int k  = blockIdx.z;   // 0..15
    int tid = threadIdx.x;
    int j = jt * 256 + tid;
    int q = a % 5, mdiv = a / 5;

    const float* Ab = A + (size_t)k * 75 * D2Z + j;
    float a2v[25], a3v[25];
    #pragma unroll
    for (int i = 0; i < 25; i++) a2v[i] = Ab[(size_t)(25 + i) * D2Z];
    #pragma unroll
    for (int i = 0; i < 25; i++) a3v[i] = Ab[(size_t)(50 + i) * D2Z];
    float a1  = Ab[(size_t)a * D2Z];
    float b1v = b1[j];

    const float* Dk = Dm + ((size_t)k * NR + a) * NR;
    float acc = 0.0f, cntv = 0.0f;

    #pragma unroll
    for (int m = 0; m < 5; m++) {
        if (m == mdiv) continue;
        int p = q + 5 * m;
        float dap = Dk[p];
        float s = a1 + a2v[p] + b1v;
        #pragma unroll
        for (int n = 0; n < 25; n++) {
            if ((n % 5) == q) continue;
            float tm = Dk[n] - dap;
            bool sel = (tm > 0.0f) && (tm <= 0.8f);
            float pre = fmaxf(s + a3v[n], 0.0f);
            float msk = sel ? 1.0f : 0.0f;
            acc = fmaf(msk, pre, acc);
            cntv += msk;
        }
    }

    atomicAdd(&G[(size_t)k * D2Z + j], acc);
    if (jt == 0 && tid == 0) atomicAdd(&cnt[k], cntv);
}

// ---------------------------------------------------------------------------
// K4a: pooled[k][col] = G[k]·W2[:,col] + cnt[k]*b2[col]
// Grid (8 coltiles, 16 tasks); 256 thr = 64 cols x 4 K-chunks of 256.
// ---------------------------------------------------------------------------
__global__ __launch_bounds__(256) void k_pooled(const float* __restrict__ G,
                                                const float* __restrict__ cnt,
                                                const float* __restrict__ W2,
                                                const float* __restrict__ b2,
                                                float* __restrict__ pooled)
{
    int bx = blockIdx.x, k = blockIdx.y;
    int tid = threadIdx.x, lane = tid & 63, kc = tid >> 6;
    int col = bx * 64 + lane;

    const float* Gk = G + (size_t)k * D2Z;
    float acc = 0.0f;
    int j0 = kc * 256;
    #pragma unroll 4
    for (int jj = j0; jj < j0 + 256; jj++)
        acc = fmaf(Gk[jj], W2[(size_t)jj * DZ + col], acc);

    __shared__ float red[4][64];
    red[kc][lane] = acc;
    __syncthreads();
    if (tid < 64) {
        float s = red[0][lane] + red[1][lane] + red[2][lane] + red[3][lane];
        s += cnt[k] * b2[col];
        pooled[(size_t)k * DZ + col] = s;
    }
}

// ---------------------------------------------------------------------------
// K4b: u[k][col] = relu(pooled[k]·W3[:,col] + b3[col])
// Grid (16 coltiles, 16 tasks); 64 cols x 4 K-chunks of 128.
// ---------------------------------------------------------------------------
__global__ __launch_bounds__(256) void k_u(const float* __restrict__ pooled,
                                           const float* __restrict__ W3,
                                           const float* __restrict__ b3,
                                           float* __restrict__ u)
{
    int bx = blockIdx.x, k = blockIdx.y;
    int tid = threadIdx.x, lane = tid & 63, kc = tid >> 6;
    int col = bx * 64 + lane;

    const float* Pk = pooled + (size_t)k * DZ;
    float acc = 0.0f;
    int s0 = kc * 128;
    #pragma unroll 4
    for (int s = s0; s < s0 + 128; s++)
        acc = fmaf(Pk[s], W3[(size_t)s * D2Z + col], acc);

    __shared__ float red[4][64];
    red[kc][lane] = acc;
    __syncthreads();
    if (tid < 64) {
        float v = red[0][lane] + red[1][lane] + red[2][lane] + red[3][lane] + b3[col];
        u[(size_t)k * D2Z + col] = fmaxf(v, 0.0f);
    }
}

// ---------------------------------------------------------------------------
// K4c: o[k][col] = u[k]·W4[:,col] + b4[col]
// Grid (8 coltiles, 16 tasks); 64 cols x 4 K-chunks of 256.
// ---------------------------------------------------------------------------
__global__ __launch_bounds__(256) void k_o(const float* __restrict__ u,
                                           const float* __restrict__ W4,
                                           const float* __restrict__ b4,
                                           float* __restrict__ o)
{
    int bx = blockIdx.x, k = blockIdx.y;
    int tid = threadIdx.x, lane = tid & 63, kc = tid >> 6;
    int col = bx * 64 + lane;

    const float* Uk = u + (size_t)k * D2Z;
    float acc = 0.0f;
    int j0 = kc * 256;
    #pragma unroll 4
    for (int jj = j0; jj < j0 + 256; jj++)
        acc = fmaf(Uk[jj], W4[(size_t)jj * DZ + col], acc);

    __shared__ float red[4][64];
    red[kc][lane] = acc;
    __syncthreads();
    if (tid < 64) {
        o[(size_t)k * DZ + col] = red[0][lane] + red[1][lane] + red[2][lane]
                                + red[3][lane] + b4[col];
    }
}

// ---------------------------------------------------------------------------
// K4d: score = o @ Wc + bc, softmax. One block per task, 64 oc x 4 K-chunks.
// ---------------------------------------------------------------------------
__global__ __launch_bounds__(256) void k_score(const float* __restrict__ o,
                                               const float* __restrict__ Wc,
                                               const float* __restrict__ bc,
                                               float* __restrict__ out)
{
    int k = blockIdx.x;
    int tid = threadIdx.x, oc = tid & 63, kc = tid >> 6;

    const float* Ok = o + (size_t)k * DZ;
    float acc = 0.0f;
    int r0 = kc * 128;
    #pragma unroll 4
    for (int rr = r0; rr < r0 + 128; rr++)
        acc = fmaf(Ok[rr], Wc[(size_t)rr * NC + oc], acc);

    __shared__ float red[4][64];
    red[kc][oc] = acc;
    __syncthreads();
    if (tid < 64) {
        float sc = bc[tid] + red[0][tid] + red[1][tid] + red[2][tid] + red[3][tid];
        float m = sc;
        #pragma unroll
        for (int off = 32; off; off >>= 1) m = fmaxf(m, __shfl_xor(m, off));
        float e = expf(sc - m);
        float ss = e;
        #pragma unroll
        for (int off = 32; off; off >>= 1) ss += __shfl_xor(ss, off);
        out[k * NC + tid] = e / ss;
    }
}

extern "C" void kernel_launch(void* const* d_in, const int* in_sizes, int n_in,
                              void* d_out, int out_size, void* d_ws, size_t ws_size,
                              hipStream_t stream)
{
    const float* x  = (const float*)d_in[0];
    const float* W1 = (const float*)d_in[1];
    const float* b1 = (const float*)d_in[2];
    const float* W2 = (const float*)d_in[3];
    const float* b2 = (const float*)d_in[4];
    const float* W3 = (const float*)d_in[5];
    const float* b3 = (const float*)d_in[6];
    const float* W4 = (const float*)d_in[7];
    const float* b4 = (const float*)d_in[8];
    const float* Wc = (const float*)d_in[9];
    const float* bc = (const float*)d_in[10];
    float* out = (float*)d_out;

    float* ws     = (float*)d_ws;
    float* Dm     = ws;                 // 10000
    float* cnt    = ws + 10000;         // 16
    float* G      = ws + 10016;         // 16384
    float* A      = ws + 26400;         // 1228800
    float* pooled = A + 1228800;        // 8192
    float* uu     = pooled + 8192;      // 16384
    float* oo     = uu + 16384;         // 8192

    hipMemsetAsync(cnt, 0, (16 + NT * D2Z) * sizeof(float), stream);

    k_dist  <<<dim3(NT, NR),    256, 0, stream>>>(x, Dm);
    k_gemm1 <<<dim3(48, 2, 8),  256, 0, stream>>>(x, W1, A);
    k_accum <<<dim3(4, NR, NT), 256, 0, stream>>>(A, Dm, b1, G, cnt);
    k_pooled<<<dim3(8, NT),     256, 0, stream>>>(G, cnt, W2, b2, pooled);
    k_u     <<<dim3(16, NT),    256, 0, stream>>>(pooled, W3, b3, uu);
    k_o     <<<dim3(8, NT),     256, 0, stream>>>(uu, W4, b4, oo);
    k_score <<<NT,              256, 0, stream>>>(oo, Wc, bc, out);
}

// Round 3
// 208.473 us; speedup vs baseline: 1.4336x; 1.2365x over previous
//
#include <hip/hip_runtime.h>
#include <math.h>

#define NT 16
#define NR 25
#define DZ 512
#define D2Z 1024
#define NC 64

typedef short bf16x8 __attribute__((ext_vector_type(8)));
typedef float f32x4  __attribute__((ext_vector_type(4)));

// Workspace layout (float offsets):
//  Dm     [16][25][25]        0        10000
//  cnt    [16]                10000    16
//  G      [16][1024]          10016    16384   (zeroed each call)
//  A      [16][3][25][1024]   26400    1228800
//  pooled [16][512]           1255200  8192
//  u      [16][1024]          1263392  16384
//  o      [16][512]           1279776  8192
//  W1h    ushort[3][1024][512] (transposed)  1287968  (786432 floats)
//  W1l    ushort[3][1024][512]               2074400  (786432 floats)
//  xh     ushort[400][512]                   2860832  (102400 floats)
//  xl     ushort[400][512]                   2963232  (102400 floats)
// total 3065632 floats = 12.26 MB

static __device__ inline unsigned short f2bf(float v) {
    union { float f; unsigned u; } x; x.f = v;
    unsigned r = x.u + 0x7fffu + ((x.u >> 16) & 1u);
    return (unsigned short)(r >> 16);
}
static __device__ inline float bf2f(unsigned short h) {
    union { float f; unsigned u; } x; x.u = ((unsigned)h) << 16; return x.f;
}

// ---------------------------------------------------------------------------
// convW: W1[1536][1024] fp32 -> W1h/W1l ushort [3][1024][512] (hi/lo bf16,
// TRANSPOSED so gemm B-fragments are k-contiguous). 64x64 tiles via LDS.
// ---------------------------------------------------------------------------
#define TP 76   // LDS tile pitch (ushorts)
__global__ __launch_bounds__(256) void k_convW(const float* __restrict__ W1,
                                               unsigned short* __restrict__ W1h,
                                               unsigned short* __restrict__ W1l)
{
    __shared__ unsigned short th[64 * TP], tl[64 * TP];
    int r0 = blockIdx.x * 64;          // 0..1472
    int j0 = blockIdx.y * 64;          // 0..960
    int c  = r0 >> 9;                  // 0..2
    int rb = r0 & 511;
    int tid = threadIdx.x;

    #pragma unroll
    for (int it = 0; it < 4; it++) {
        int rl = (tid >> 4) + it * 16;
        int jj = (tid & 15) * 4;
        float4 v = *(const float4*)(W1 + (size_t)(r0 + rl) * D2Z + j0 + jj);
        unsigned short h0 = f2bf(v.x), h1 = f2bf(v.y), h2 = f2bf(v.z), h3 = f2bf(v.w);
        th[rl * TP + jj + 0] = h0; tl[rl * TP + jj + 0] = f2bf(v.x - bf2f(h0));
        th[rl * TP + jj + 1] = h1; tl[rl * TP + jj + 1] = f2bf(v.y - bf2f(h1));
        th[rl * TP + jj + 2] = h2; tl[rl * TP + jj + 2] = f2bf(v.z - bf2f(h2));
        th[rl * TP + jj + 3] = h3; tl[rl * TP + jj + 3] = f2bf(v.w - bf2f(h3));
    }
    __syncthreads();

    #pragma unroll
    for (int it = 0; it < 4; it++) {
        int jl = (tid >> 4) + it * 16;
        int r4 = (tid & 15) * 4;
        ushort4 hv = make_ushort4(th[(r4+0)*TP + jl], th[(r4+1)*TP + jl],
                                  th[(r4+2)*TP + jl], th[(r4+3)*TP + jl]);
        ushort4 lv = make_ushort4(tl[(r4+0)*TP + jl], tl[(r4+1)*TP + jl],
                                  tl[(r4+2)*TP + jl], tl[(r4+3)*TP + jl]);
        size_t dst = ((size_t)c * D2Z + j0 + jl) * DZ + rb + r4;
        *(ushort4*)(W1h + dst) = hv;
        *(ushort4*)(W1l + dst) = lv;
    }
}

// ---------------------------------------------------------------------------
// convX: x[400][512] fp32 -> xh/xl ushort [400][512] (layout preserved).
// ---------------------------------------------------------------------------
__global__ __launch_bounds__(256) void k_convX(const float* __restrict__ x,
                                               unsigned short* __restrict__ xh,
                                               unsigned short* __restrict__ xl)
{
    size_t i8 = ((size_t)blockIdx.x * 256 + threadIdx.x) * 8;
    float4 a = *(const float4*)(x + i8);
    float4 b = *(const float4*)(x + i8 + 4);
    unsigned short h;
    ushort4 ha, hb, la, lb;
    h = f2bf(a.x); ha.x = h; la.x = f2bf(a.x - bf2f(h));
    h = f2bf(a.y); ha.y = h; la.y = f2bf(a.y - bf2f(h));
    h = f2bf(a.z); ha.z = h; la.z = f2bf(a.z - bf2f(h));
    h = f2bf(a.w); ha.w = h; la.w = f2bf(a.w - bf2f(h));
    h = f2bf(b.x); hb.x = h; lb.x = f2bf(b.x - bf2f(h));
    h = f2bf(b.y); hb.y = h; lb.y = f2bf(b.y - bf2f(h));
    h = f2bf(b.z); hb.z = h; lb.z = f2bf(b.z - bf2f(h));
    h = f2bf(b.w); hb.w = h; lb.w = f2bf(b.w - bf2f(h));
    *(ushort4*)(xh + i8)     = ha;  *(ushort4*)(xh + i8 + 4) = hb;
    *(ushort4*)(xl + i8)     = la;  *(ushort4*)(xl + i8 + 4) = lb;
}

// ---------------------------------------------------------------------------
// K1: normalized pairwise distances (unchanged, verified).
// ---------------------------------------------------------------------------
__global__ __launch_bounds__(256) void k_dist(const float* __restrict__ x,
                                              float* __restrict__ Dm)
{
    int k = blockIdx.x, a = blockIdx.y;
    int lane = threadIdx.x & 63;
    int w    = threadIdx.x >> 6;
    const float* xk = x + (size_t)k * NR * DZ;

    const float4* xap = (const float4*)(xk + a * DZ);
    float4 a0 = xap[lane];
    float4 a1 = xap[lane + 64];

    float sa = a0.x*a0.x + a0.y*a0.y + a0.z*a0.z + a0.w*a0.w
             + a1.x*a1.x + a1.y*a1.y + a1.z*a1.z + a1.w*a1.w;
    #pragma unroll
    for (int off = 32; off; off >>= 1) sa += __shfl_xor(sa, off);
    float inva = 1.0f / sqrtf(sa);
    a0.x *= inva; a0.y *= inva; a0.z *= inva; a0.w *= inva;
    a1.x *= inva; a1.y *= inva; a1.z *= inva; a1.w *= inva;
    float sqa = a0.x*a0.x + a0.y*a0.y + a0.z*a0.z + a0.w*a0.w
              + a1.x*a1.x + a1.y*a1.y + a1.z*a1.z + a1.w*a1.w;
    #pragma unroll
    for (int off = 32; off; off >>= 1) sqa += __shfl_xor(sqa, off);

    for (int j = w; j < NR; j += 4) {
        const float4* xjp = (const float4*)(xk + j * DZ);
        float4 j0 = xjp[lane];
        float4 j1 = xjp[lane + 64];
        float sj = j0.x*j0.x + j0.y*j0.y + j0.z*j0.z + j0.w*j0.w
                 + j1.x*j1.x + j1.y*j1.y + j1.z*j1.z + j1.w*j1.w;
        #pragma unroll
        for (int off = 32; off; off >>= 1) sj += __shfl_xor(sj, off);
        float invj = 1.0f / sqrtf(sj);
        j0.x *= invj; j0.y *= invj; j0.z *= invj; j0.w *= invj;
        j1.x *= invj; j1.y *= invj; j1.z *= invj; j1.w *= invj;

        float sqj = j0.x*j0.x + j0.y*j0.y + j0.z*j0.z + j0.w*j0.w
                  + j1.x*j1.x + j1.y*j1.y + j1.z*j1.z + j1.w*j1.w;
        float dij = a0.x*j0.x + a0.y*j0.y + a0.z*j0.z + a0.w*j0.w
                  + a1.x*j1.x + a1.y*j1.y + a1.z*j1.z + a1.w*j1.w;
        #pragma unroll
        for (int off = 32; off; off >>= 1) {
            sqj += __shfl_xor(sqj, off);
            dij += __shfl_xor(dij, off);
        }
        float d2 = sqa + sqj - 2.0f * dij;
        float d  = sqrtf(fmaxf(d2, 0.0f));
        if (lane == 0) Dm[((size_t)k * NR + a) * NR + j] = d;
    }
}

// ---------------------------------------------------------------------------
// K2: split-bf16 MFMA GEMM. C[m][n] = sum_k x[m][k]*W1map[k][n],
// m in [0,400), n in [0,3072), K=512. C = hh + hl + lh (bf16 hi/lo).
// Block tile 32m x 128n, BK=64, 4 waves (2x2 of 16m x 64n).
// Grid 312 1-D: mt = bid/24, nt = bid%24 (same-nt blocks share bid%8 -> XCD).
// ---------------------------------------------------------------------------
#define XP 72   // xs pitch (ushorts), 144 B rows -> 16B-aligned b128 frags
#define WSP 72  // ws pitch
__global__ __launch_bounds__(256) void k_gemm1(const unsigned short* __restrict__ xh,
                                               const unsigned short* __restrict__ xl,
                                               const unsigned short* __restrict__ W1h,
                                               const unsigned short* __restrict__ W1l,
                                               float* __restrict__ A)
{
    __shared__ unsigned short xs_h[32 * XP], xs_l[32 * XP];
    __shared__ unsigned short ws_h[128 * WSP], ws_l[128 * WSP];

    int bid = blockIdx.x;
    int mt = bid / 24, nt = bid % 24;
    int m0 = mt * 32;
    int n0 = nt * 128;
    int c  = n0 >> 10;
    int j0 = n0 & 1023;

    int tid  = threadIdx.x;
    int lane = tid & 63;
    int wv   = tid >> 6;
    int wm   = wv >> 1, wn = wv & 1;
    int q    = lane >> 4;     // quad
    int ln16 = lane & 15;

    f32x4 acc[4];
    #pragma unroll
    for (int t = 0; t < 4; t++) acc[t] = (f32x4){0.f, 0.f, 0.f, 0.f};

    // staging indices
    int xrow = tid >> 3;              // 0..31
    int xkg  = (tid & 7) * 8;         // 0..56
    const uint4 zero4 = make_uint4(0u, 0u, 0u, 0u);

    for (int kk = 0; kk < 8; kk++) {
        int kbase = kk * 64;
        // stage x tile (32 x 64, hi+lo)
        {
            int gm = m0 + xrow;
            uint4 vh = zero4, vl = zero4;
            if (gm < 400) {
                size_t off = (size_t)gm * DZ + kbase + xkg;
                vh = *(const uint4*)(xh + off);
                vl = *(const uint4*)(xl + off);
            }
            *(uint4*)&xs_h[xrow * XP + xkg] = vh;
            *(uint4*)&xs_l[xrow * XP + xkg] = vl;
        }
        // stage W1 tile (128n x 64k, hi+lo) from transposed W1h/W1l
        #pragma unroll
        for (int it = 0; it < 4; it++) {
            int g  = tid + 256 * it;      // 0..1023
            int nl = g >> 3;              // 0..127
            int kg = (g & 7) * 8;
            size_t off = ((size_t)c * D2Z + j0 + nl) * DZ + kbase + kg;
            *(uint4*)&ws_h[nl * WSP + kg] = *(const uint4*)(W1h + off);
            *(uint4*)&ws_l[nl * WSP + kg] = *(const uint4*)(W1l + off);
        }
        __syncthreads();

        #pragma unroll
        for (int ks = 0; ks < 2; ks++) {
            int ko = ks * 32 + q * 8;
            bf16x8 a_h = *(const bf16x8*)&xs_h[(wm * 16 + ln16) * XP + ko];
            bf16x8 a_l = *(const bf16x8*)&xs_l[(wm * 16 + ln16) * XP + ko];
            #pragma unroll
            for (int t = 0; t < 4; t++) {
                int nl = wn * 64 + t * 16 + ln16;
                bf16x8 b_h = *(const bf16x8*)&ws_h[nl * WSP + ko];
                bf16x8 b_l = *(const bf16x8*)&ws_l[nl * WSP + ko];
                acc[t] = __builtin_amdgcn_mfma_f32_16x16x32_bf16(a_h, b_h, acc[t], 0, 0, 0);
                acc[t] = __builtin_amdgcn_mfma_f32_16x16x32_bf16(a_h, b_l, acc[t], 0, 0, 0);
                acc[t] = __builtin_amdgcn_mfma_f32_16x16x32_bf16(a_l, b_h, acc[t], 0, 0, 0);
            }
        }
        __syncthreads();
    }

    // epilogue: C[m][n] -> A[k][c][i][j]; row m = m0+wm*16+q*4+r, col j0+nl
    #pragma unroll
    for (int t = 0; t < 4; t++) {
        int j = j0 + wn * 64 + t * 16 + ln16;
        #pragma unroll
        for (int r = 0; r < 4; r++) {
            int m = m0 + wm * 16 + q * 4 + r;
            if (m < 400) {
                int kT = m / 25, i = m % 25;
                A[(((size_t)kT * 3 + c) * NR + i) * D2Z + j] = acc[t][r];
            }
        }
    }
}

// ---------------------------------------------------------------------------
// K3: masked relu-accumulate; 5 anchors per block, atomics into zeroed G/cnt.
// Grid (4 jtiles, 5 anchor-groups, 16 tasks).
// ---------------------------------------------------------------------------
__global__ __launch_bounds__(256) void k_accum(const float* __restrict__ A,
                                               const float* __restrict__ Dm,
                                               const float* __restrict__ b1,
                                               float* __restrict__ G,
                                               float* __restrict__ cnt)
{
    int jt = blockIdx.x;   // 0..3
    int ag = blockIdx.y;   // 0..4
    int k  = blockIdx.z;   // 0..15
    int tid = threadIdx.x;
    int j = jt * 256 + tid;

    const float* Ab = A + (size_t)k * 75 * D2Z + j;
    float a2v[25], a3v[25];
    #pragma unroll
    for (int i = 0; i < 25; i++) a2v[i] = Ab[(size_t)(25 + i) * D2Z];
    #pragma unroll
    for (int i = 0; i < 25; i++) a3v[i] = Ab[(size_t)(50 + i) * D2Z];
    float b1v = b1[j];

    float acc = 0.0f, cntv = 0.0f;
    for (int qa = 0; qa < 5; qa++) {
        int a = ag * 5 + qa;          // label q = qa, a/5 = ag
        float a1 = Ab[(size_t)a * D2Z];
        const float* Dk = Dm + ((size_t)k * NR + a) * NR;
        #pragma unroll
        for (int m = 0; m < 5; m++) {
            if (m == ag) continue;
            int p = qa + 5 * m;
            float dap = Dk[p];
            float s = a1 + a2v[p] + b1v;
            #pragma unroll
            for (int n = 0; n < 25; n++) {
                if ((n % 5) == qa) continue;
                float tm = Dk[n] - dap;
                bool sel = (tm > 0.0f) && (tm <= 0.8f);
                float pre = fmaxf(s + a3v[n], 0.0f);
                float msk = sel ? 1.0f : 0.0f;
                acc = fmaf(msk, pre, acc);
                cntv += msk;
            }
        }
    }

    atomicAdd(&G[(size_t)k * D2Z + j], acc);
    if (jt == 0 && tid == 0) atomicAdd(&cnt[k], cntv);
}

// ---------------------------------------------------------------------------
// Tail (unchanged from R2, verified).
// ---------------------------------------------------------------------------
__global__ __launch_bounds__(256) void k_pooled(const float* __restrict__ G,
                                                const float* __restrict__ cnt,
                                                const float* __restrict__ W2,
                                                const float* __restrict__ b2,
                                                float* __restrict__ pooled)
{
    int bx = blockIdx.x, k = blockIdx.y;
    int tid = threadIdx.x, lane = tid & 63, kc = tid >> 6;
    int col = bx * 64 + lane;

    const float* Gk = G + (size_t)k * D2Z;
    float acc = 0.0f;
    int j0 = kc * 256;
    #pragma unroll 4
    for (int jj = j0; jj < j0 + 256; jj++)
        acc = fmaf(Gk[jj], W2[(size_t)jj * DZ + col], acc);

    __shared__ float red[4][64];
    red[kc][lane] = acc;
    __syncthreads();
    if (tid < 64) {
        float s = red[0][lane] + red[1][lane] + red[2][lane] + red[3][lane];
        s += cnt[k] * b2[col];
        pooled[(size_t)k * DZ + col] = s;
    }
}

__global__ __launch_bounds__(256) void k_u(const float* __restrict__ pooled,
                                           const float* __restrict__ W3,
                                           const float* __restrict__ b3,
                                           float* __restrict__ u)
{
    int bx = blockIdx.x, k = blockIdx.y;
    int tid = threadIdx.x, lane = tid & 63, kc = tid >> 6;
    int col = bx * 64 + lane;

    const float* Pk = pooled + (size_t)k * DZ;
    float acc = 0.0f;
    int s0 = kc * 128;
    #pragma unroll 4
    for (int s = s0; s < s0 + 128; s++)
        acc = fmaf(Pk[s], W3[(size_t)s * D2Z + col], acc);

    __shared__ float red[4][64];
    red[kc][lane] = acc;
    __syncthreads();
    if (tid < 64) {
        float v = red[0][lane] + red[1][lane] + red[2][lane] + red[3][lane] + b3[col];
        u[(size_t)k * D2Z + col] = fmaxf(v, 0.0f);
    }
}

__global__ __launch_bounds__(256) void k_o(const float* __restrict__ u,
                                           const float* __restrict__ W4,
                                           const float* __restrict__ b4,
                                           float* __restrict__ o)
{
    int bx = blockIdx.x, k = blockIdx.y;
    int tid = threadIdx.x, lane = tid & 63, kc = tid >> 6;
    int col = bx * 64 + lane;

    const float* Uk = u + (size_t)k * D2Z;
    float acc = 0.0f;
    int j0 = kc * 256;
    #pragma unroll 4
    for (int jj = j0; jj < j0 + 256; jj++)
        acc = fmaf(Uk[jj], W4[(size_t)jj * DZ + col], acc);

    __shared__ float red[4][64];
    red[kc][lane] = acc;
    __syncthreads();
    if (tid < 64) {
        o[(size_t)k * DZ + col] = red[0][lane] + red[1][lane] + red[2][lane]
                                + red[3][lane] + b4[col];
    }
}

__global__ __launch_bounds__(256) void k_score(const float* __restrict__ o,
                                               const float* __restrict__ Wc,
                                               const float* __restrict__ bc,
                                               float* __restrict__ out)
{
    int k = blockIdx.x;
    int tid = threadIdx.x, oc = tid & 63, kc = tid >> 6;

    const float* Ok = o + (size_t)k * DZ;
    float acc = 0.0f;
    int r0 = kc * 128;
    #pragma unroll 4
    for (int rr = r0; rr < r0 + 128; rr++)
        acc = fmaf(Ok[rr], Wc[(size_t)rr * NC + oc], acc);

    __shared__ float red[4][64];
    red[kc][oc] = acc;
    __syncthreads();
    if (tid < 64) {
        float sc = bc[tid] + red[0][tid] + red[1][tid] + red[2][tid] + red[3][tid];
        float m = sc;
        #pragma unroll
        for (int off = 32; off; off >>= 1) m = fmaxf(m, __shfl_xor(m, off));
        float e = expf(sc - m);
        float ss = e;
        #pragma unroll
        for (int off = 32; off; off >>= 1) ss += __shfl_xor(ss, off);
        out[k * NC + tid] = e / ss;
    }
}

extern "C" void kernel_launch(void* const* d_in, const int* in_sizes, int n_in,
                              void* d_out, int out_size, void* d_ws, size_t ws_size,
                              hipStream_t stream)
{
    const float* x  = (const float*)d_in[0];
    const float* W1 = (const float*)d_in[1];
    const float* b1 = (const float*)d_in[2];
    const float* W2 = (const float*)d_in[3];
    const float* b2 = (const float*)d_in[4];
    const float* W3 = (const float*)d_in[5];
    const float* b3 = (const float*)d_in[6];
    const float* W4 = (const float*)d_in[7];
    const float* b4 = (const float*)d_in[8];
    const float* Wc = (const float*)d_in[9];
    const float* bc = (const float*)d_in[10];
    float* out = (float*)d_out;

    float* ws     = (float*)d_ws;
    float* Dm     = ws;                       // 10000
    float* cnt    = ws + 10000;               // 16
    float* G      = ws + 10016;               // 16384
    float* A      = ws + 26400;               // 1228800
    float* pooled = A + 1228800;              // 8192
    float* uu     = pooled + 8192;            // 16384
    float* oo     = uu + 16384;               // 8192
    unsigned short* W1h = (unsigned short*)(oo + 8192);
    unsigned short* W1l = W1h + 3 * D2Z * DZ; // 1572864 each
    unsigned short* xh  = W1l + 3 * D2Z * DZ;
    unsigned short* xl  = xh + 400 * DZ;      // 204800 each

    hipMemsetAsync(cnt, 0, (16 + NT * D2Z) * sizeof(float), stream);

    k_convW <<<dim3(24, 16),   256, 0, stream>>>(W1, W1h, W1l);
    k_convX <<<100,            256, 0, stream>>>(x, xh, xl);
    k_dist  <<<dim3(NT, NR),   256, 0, stream>>>(x, Dm);
    k_gemm1 <<<312,            256, 0, stream>>>(xh, xl, W1h, W1l, A);
    k_accum <<<dim3(4, 5, NT), 256, 0, stream>>>(A, Dm, b1, G, cnt);
    k_pooled<<<dim3(8, NT),    256, 0, stream>>>(G, cnt, W2, b2, pooled);
    k_u     <<<dim3(16, NT),   256, 0, stream>>>(pooled, W3, b3, uu);
    k_o     <<<dim3(8, NT),    256, 0, stream>>>(uu, W4, b4, oo);
    k_score <<<NT,             256, 0, stream>>>(oo, Wc, bc, out);
}